// Round 6
// baseline (174.157 us; speedup 1.0000x reference)
//
#include <hip/hip_runtime.h>

// Problem dims (fixed by reference)
#define Bq 32
#define Sq 64
#define Iq 256
#define Hq 256
#define Oq 128
#define Fq 512          // Iq + Hq
#define WPB 8           // workgroups per batch
#define NT 512          // threads per workgroup
#define PRE_S 56        // steps with x preloaded in LDS

// tanh via v_exp_f32: 1 - 2/(e^{2x}+1). Saturates to +/-1 at +/-inf (no NaN).
__device__ __forceinline__ float fast_tanh(float v) {
    const float e = __expf(2.0f * v);
    return 1.0f - __fdividef(2.0f, e + 1.0f);
}

// R5 skeleton with the per-step loop body FROZEN (R3/R4 proved splitting the
// fused pre+nsq critical loop regresses). R6 deltas attack the exchange path:
//  (A) own-row short-circuit: lane0 writes hn into next-parity LDS during
//      critical; pollers never poll this wg's own 32 rows (removes a
//      self-MALL round trip from the barrier path).
//  (B) fast_tanh + __frsqrt_rn on the critical chain.
//  (C) dual-phase polling for t<PRE_S: idle x-threads (tid<224) form a second
//      poller per remote slot, staggered ~320cyc via s_sleep(5); an LDS
//      step-flag lets EITHER poller release both (detect = min of samplers).
__global__ __launch_bounds__(NT, 2) void stpn_main(
    const float* __restrict__ x,     // (B,S,I)
    const float* __restrict__ w,     // (H,F)
    const float* __restrict__ wl,    // (H,F)
    const float* __restrict__ wgm,   // (H,F)
    const float* __restrict__ bias,  // (H)
    const float* __restrict__ ow,    // (O,H)
    const float* __restrict__ ob,    // (O)
    float* __restrict__ out,         // [tag(B*O) | h_fin(B*H) | f_fin(B*H*F)]
    unsigned long long* __restrict__ hb) // [2][B][H] (tag<<32|bits) slots
{
    const int blk   = blockIdx.x;
    const int b     = blk & 31;       // all 8 wgs of a batch -> same XCD heuristic
    const int chunk = blk >> 5;       // 0..7
    const int h0    = chunk * 32;
    const int tid   = threadIdx.x;
    const int lr    = tid & 15;       // lane within row
    const int r     = tid >> 4;       // row 0..31
    const int row   = h0 + r;

    __shared__ float ti[2][Fq];           // staging buf: x (t>=PRE_S) | h_{t-1}
    __shared__ float xall[PRE_S * Iq];    // x_0..x_55
    __shared__ int   pollflag[Hq];        // last step detected per slot

    // Static params + fast-weight state in registers for all 64 steps.
    float fw[32], fl[32], fg[32], ff[32];
    const size_t rowoff = (size_t)row * Fq;
#pragma unroll
    for (int j = 0; j < 8; ++j) {
        const int c = 4 * lr + 64 * j;
        *(float4*)&fw[4*j] = *(const float4*)(w   + rowoff + c);
        *(float4*)&fl[4*j] = *(const float4*)(wl  + rowoff + c);
        *(float4*)&fg[4*j] = *(const float4*)(wgm + rowoff + c);
    }
#pragma unroll
    for (int j = 0; j < 32; ++j) ff[j] = 0.f;

    // Prologue x preload: 56*256/4 = 3584 float4 = 512 threads x 7.
    {
        const float4* xs = (const float4*)(x + (size_t)b * Sq * Iq);
        float4* xd = (float4*)xall;
#pragma unroll
        for (int k = 0; k < (PRE_S * Iq / 4) / NT; ++k)
            xd[tid + NT * k] = xs[tid + NT * k];
    }
    if (tid < Hq) pollflag[tid] = 0;
    const float brow = bias[row];
    const float* xb = x + (size_t)b * Sq * Iq;

    for (int t = 0; t < Sq; ++t) {
        const int p = t & 1;
        // ---- staging ----
        if (tid < Iq) {
            if (t >= PRE_S) {
                ti[p][tid] = xb[(size_t)t * Iq + tid];
            } else if (t > 0 && tid < Hq - 32) {
                // (C) secondary poller, staggered; remote slots only.
                const int hh = tid + (tid >= h0 ? 32 : 0);
                unsigned long long* slot =
                    hb + (size_t)((t - 1) & 1) * Bq * Hq + (size_t)b * Hq + hh;
                volatile int* fl_ = &pollflag[hh];
                __builtin_amdgcn_s_sleep(5);
                if (*fl_ != t) {
                    do {
                        unsigned long long v =
                            __hip_atomic_load(slot, __ATOMIC_RELAXED,
                                              __HIP_MEMORY_SCOPE_AGENT);
                        if ((unsigned)(v >> 32) == (unsigned)t) {
                            ti[p][Iq + hh] =
                                __uint_as_float((unsigned)(v & 0xffffffffu));
                            *fl_ = t;
                            break;
                        }
                    } while (*fl_ != t);
                }
            }
        } else {
            const int hh = tid - Iq;
            if (t == 0) {
                ti[p][Iq + hh] = 0.f;
            } else if (hh < h0 || hh >= h0 + 32) {       // (A) skip own rows
                unsigned long long* slot =
                    hb + (size_t)((t - 1) & 1) * Bq * Hq + (size_t)b * Hq + hh;
                volatile int* fl_ = &pollflag[hh];
                do {
                    unsigned long long v =
                        __hip_atomic_load(slot, __ATOMIC_RELAXED,
                                          __HIP_MEMORY_SCOPE_AGENT);
                    if ((unsigned)(v >> 32) == (unsigned)t) {
                        ti[p][Iq + hh] =
                            __uint_as_float((unsigned)(v & 0xffffffffu));
                        *fl_ = t;
                        break;
                    }
                } while (*fl_ != t);
            }
            // own rows, t>0: already written to LDS by critical of step t-1.
        }
        __syncthreads();                 // the only barrier per step

        const float* xpart = (t < PRE_S) ? (xall + t * Iq) : &ti[p][0];
        const float* hpart = &ti[p][Iq];

        // ---- critical: fused pre+nsq -> butterflies -> inv -> tanh -> publish
        float pre = 0.f, nsq = 0.f;
#pragma unroll
        for (int j = 0; j < 4; ++j) {
            const float4 tv = *(const float4*)&xpart[4 * lr + 64 * j];
            float tw;
            tw = fw[4*j+0] + ff[4*j+0]; pre = fmaf(tv.x, tw, pre); nsq = fmaf(tw, tw, nsq);
            tw = fw[4*j+1] + ff[4*j+1]; pre = fmaf(tv.y, tw, pre); nsq = fmaf(tw, tw, nsq);
            tw = fw[4*j+2] + ff[4*j+2]; pre = fmaf(tv.z, tw, pre); nsq = fmaf(tw, tw, nsq);
            tw = fw[4*j+3] + ff[4*j+3]; pre = fmaf(tv.w, tw, pre); nsq = fmaf(tw, tw, nsq);
        }
#pragma unroll
        for (int j = 4; j < 8; ++j) {
            const float4 tv = *(const float4*)&hpart[4 * lr + 64 * (j - 4)];
            float tw;
            tw = fw[4*j+0] + ff[4*j+0]; pre = fmaf(tv.x, tw, pre); nsq = fmaf(tw, tw, nsq);
            tw = fw[4*j+1] + ff[4*j+1]; pre = fmaf(tv.y, tw, pre); nsq = fmaf(tw, tw, nsq);
            tw = fw[4*j+2] + ff[4*j+2]; pre = fmaf(tv.z, tw, pre); nsq = fmaf(tw, tw, nsq);
            tw = fw[4*j+3] + ff[4*j+3]; pre = fmaf(tv.w, tw, pre); nsq = fmaf(tw, tw, nsq);
        }
#pragma unroll
        for (int m = 1; m < 16; m <<= 1) {
            pre += __shfl_xor(pre, m, 16);
            nsq += __shfl_xor(nsq, m, 16);
        }
        const float inv = __frsqrt_rn(nsq);          // (B) nsq >= |w_row|^2 > 0
        const float hn  = fast_tanh(fmaf(pre, inv, brow));

        if (lr == 0) {
            if (t < Sq - 1)
                ti[(t + 1) & 1][Iq + row] = hn;      // (A) local short-circuit
            const unsigned long long pk =
                ((unsigned long long)(unsigned)(t + 1) << 32) |
                (unsigned long long)__float_as_uint(hn);
            __hip_atomic_store(
                hb + (size_t)p * Bq * Hq + (size_t)b * Hq + row, pk,
                __ATOMIC_RELAXED, __HIP_MEMORY_SCOPE_AGENT);
        }

        // ---- shadow: f update ----
#pragma unroll
        for (int j = 0; j < 4; ++j) {
            const float4 tv = *(const float4*)&xpart[4 * lr + 64 * j];
            ff[4*j+0] = fmaf(fl[4*j+0], ff[4*j+0] * inv, fg[4*j+0] * (hn * tv.x));
            ff[4*j+1] = fmaf(fl[4*j+1], ff[4*j+1] * inv, fg[4*j+1] * (hn * tv.y));
            ff[4*j+2] = fmaf(fl[4*j+2], ff[4*j+2] * inv, fg[4*j+2] * (hn * tv.z));
            ff[4*j+3] = fmaf(fl[4*j+3], ff[4*j+3] * inv, fg[4*j+3] * (hn * tv.w));
        }
#pragma unroll
        for (int j = 4; j < 8; ++j) {
            const float4 tv = *(const float4*)&hpart[4 * lr + 64 * (j - 4)];
            ff[4*j+0] = fmaf(fl[4*j+0], ff[4*j+0] * inv, fg[4*j+0] * (hn * tv.x));
            ff[4*j+1] = fmaf(fl[4*j+1], ff[4*j+1] * inv, fg[4*j+1] * (hn * tv.y));
            ff[4*j+2] = fmaf(fl[4*j+2], ff[4*j+2] * inv, fg[4*j+2] * (hn * tv.z));
            ff[4*j+3] = fmaf(fl[4*j+3], ff[4*j+3] * inv, fg[4*j+3] * (hn * tv.w));
        }
    }

    // ---- f_fin: 16 lanes x float4 per row chunk ----
    float* fo = out + Bq * Oq + Bq * Hq + (size_t)b * Hq * Fq + rowoff;
#pragma unroll
    for (int j = 0; j < 8; ++j) {
        const int c = 4 * lr + 64 * j;
        *(float4*)(fo + c) = *(const float4*)&ff[4*j];
    }

    // ---- epilogue (chunk-0 wg per batch): h_fin + tag_space ----
    if (chunk == 0) {
        if (tid < Hq) {
            unsigned long long* slot =
                hb + (size_t)1 * Bq * Hq + (size_t)b * Hq + tid;  // t=63 -> parity 1
            unsigned long long v;
            do {
                v = __hip_atomic_load(slot, __ATOMIC_RELAXED,
                                      __HIP_MEMORY_SCOPE_AGENT);
            } while ((unsigned)(v >> 32) != (unsigned)Sq);
            const float hv = __uint_as_float((unsigned)(v & 0xffffffffu));
            ti[0][tid] = hv;                              // ti[0] is free here
            out[Bq * Oq + (size_t)b * Hq + tid] = hv;     // h_fin
        }
        __syncthreads();
        // 512 threads = 128 outputs x 4 lanes; lane l sums cols 16k+4l..+3.
        const int o = tid >> 2;
        const int l = tid & 3;
        const float* wr = ow + (size_t)o * Hq;
        float acc = 0.f;
#pragma unroll
        for (int k = 0; k < 16; ++k) {
            const int cc = 16 * k + 4 * l;
            const float4 w4 = *(const float4*)(wr + cc);
            const float4 h4 = *(const float4*)&ti[0][cc];
            acc += w4.x * h4.x + w4.y * h4.y + w4.z * h4.z + w4.w * h4.w;
        }
        acc += __shfl_xor(acc, 1, 4);
        acc += __shfl_xor(acc, 2, 4);
        if (l == 0) out[(size_t)b * Oq + o] = acc + ob[o];
    }
}

extern "C" void kernel_launch(void* const* d_in, const int* in_sizes, int n_in,
                              void* d_out, int out_size, void* d_ws, size_t ws_size,
                              hipStream_t stream)
{
    const float* x    = (const float*)d_in[0];
    const float* w    = (const float*)d_in[1];
    const float* wl   = (const float*)d_in[2];
    const float* wgm  = (const float*)d_in[3];
    const float* bias = (const float*)d_in[4];
    const float* ow   = (const float*)d_in[5];
    const float* ob   = (const float*)d_in[6];
    float* out = (float*)d_out;

    // Zero the (tag,val) h-exchange slots: 2 * B * H * 8 bytes = 128 KB.
    hipMemsetAsync(d_ws, 0, 2 * Bq * Hq * sizeof(unsigned long long), stream);

    stpn_main<<<Bq * WPB, NT, 0, stream>>>(x, w, wl, wgm, bias, ow, ob, out,
                                           (unsigned long long*)d_ws);
}

// Round 7
// 172.934 us; speedup vs baseline: 1.0071x; 1.0071x over previous
//
#include <hip/hip_runtime.h>

// Problem dims (fixed by reference)
#define Bq 32
#define Sq 64
#define Iq 256
#define Hq 256
#define Oq 128
#define Fq 512          // Iq + Hq
#define WPB 8           // workgroups per batch
#define NT 512          // threads per workgroup
#define PRE_S 56        // steps with x preloaded in LDS

// tanh via v_exp_f32: 1 - 2/(e^{2x}+1). Saturates to +/-1 at +/-inf (no NaN).
__device__ __forceinline__ float fast_tanh(float v) {
    const float e = __expf(2.0f * v);
    return 1.0f - __fdividef(2.0f, e + 1.0f);
}

// L1-bypassed, L2-served 8B load (sc0 only -- NOT agent/sc1, so it can hit
// the XCD-local L2 written through by a plain store from a peer CU).
__device__ __forceinline__ unsigned long long load_u64_l2(
    const unsigned long long* p) {
    unsigned long long v;
    asm volatile("global_load_dwordx2 %0, %1, off sc0\n\t"
                 "s_waitcnt vmcnt(0)"
                 : "=v"(v) : "v"(p) : "memory");
    return v;
}
// Plain 8B store: write-through to the producer's XCD L2 (no sc bits).
__device__ __forceinline__ void store_u64_l2(unsigned long long* p,
                                             unsigned long long v) {
    asm volatile("global_store_dwordx2 %0, %1, off" :: "v"(p), "v"(v)
                 : "memory");
}

// R5 skeleton, per-step loop body FROZEN (R3/R4: splitting the fused critical
// loop regresses; R6: dual-phase polling regresses). Deltas:
//  (A) own-row short-circuit via LDS (kept from R6 -- strictly removes work).
//  (B) fast_tanh + __frsqrt_rn on the critical chain (kept from R6).
//  (D) NEW: same-XCD L2 fast-path h-exchange. Producers publish (tag|val)
//      to a fast mirror with a plain store (lands in XCD L2) AND to the safe
//      slot with an agent-scope atomic (MALL). Pollers try the sc0 L2 load
//      first, fall back to the agent load. blk&31 batch mapping puts all 8
//      wgs of a batch on one XCD under round-robin dispatch -> ~200cyc RT
//      instead of ~700-900. If dispatch differs, fast slots never match and
//      the safe path alone makes progress (placement-independent correctness).
__global__ __launch_bounds__(NT, 2) void stpn_main(
    const float* __restrict__ x,     // (B,S,I)
    const float* __restrict__ w,     // (H,F)
    const float* __restrict__ wl,    // (H,F)
    const float* __restrict__ wgm,   // (H,F)
    const float* __restrict__ bias,  // (H)
    const float* __restrict__ ow,    // (O,H)
    const float* __restrict__ ob,    // (O)
    float* __restrict__ out,         // [tag(B*O) | h_fin(B*H) | f_fin(B*H*F)]
    unsigned long long* __restrict__ hb) // [safe 2*B*H | fast 2*B*H] u64 slots
{
    const int blk   = blockIdx.x;
    const int b     = blk & 31;       // all 8 wgs of a batch: blk%8 == b%8
    const int chunk = blk >> 5;       // 0..7
    const int h0    = chunk * 32;
    const int tid   = threadIdx.x;
    const int lr    = tid & 15;       // lane within row
    const int r     = tid >> 4;       // row 0..31
    const int row   = h0 + r;

    unsigned long long* hsafe = hb;
    unsigned long long* hfast = hb + 2 * Bq * Hq;

    __shared__ float ti[2][Fq];           // staging buf: x (t>=PRE_S) | h_{t-1}
    __shared__ float xall[PRE_S * Iq];    // x_0..x_55

    // Static params + fast-weight state in registers for all 64 steps.
    float fw[32], fl[32], fg[32], ff[32];
    const size_t rowoff = (size_t)row * Fq;
#pragma unroll
    for (int j = 0; j < 8; ++j) {
        const int c = 4 * lr + 64 * j;
        *(float4*)&fw[4*j] = *(const float4*)(w   + rowoff + c);
        *(float4*)&fl[4*j] = *(const float4*)(wl  + rowoff + c);
        *(float4*)&fg[4*j] = *(const float4*)(wgm + rowoff + c);
    }
#pragma unroll
    for (int j = 0; j < 32; ++j) ff[j] = 0.f;

    // Prologue x preload: 56*256/4 = 3584 float4 = 512 threads x 7.
    {
        const float4* xs = (const float4*)(x + (size_t)b * Sq * Iq);
        float4* xd = (float4*)xall;
#pragma unroll
        for (int k = 0; k < (PRE_S * Iq / 4) / NT; ++k)
            xd[tid + NT * k] = xs[tid + NT * k];
    }
    const float brow = bias[row];
    const float* xb = x + (size_t)b * Sq * Iq;

    for (int t = 0; t < Sq; ++t) {
        const int p = t & 1;
        // ---- staging ----
        if (tid < Iq) {
            if (t >= PRE_S) ti[p][tid] = xb[(size_t)t * Iq + tid];
        } else {
            const int hh = tid - Iq;
            if (t == 0) {
                ti[p][Iq + hh] = 0.f;
            } else if (hh < h0 || hh >= h0 + 32) {       // (A) skip own rows
                const size_t idx =
                    (size_t)((t - 1) & 1) * Bq * Hq + (size_t)b * Hq + hh;
                const unsigned long long* fs = hfast + idx;
                const unsigned long long* ss = hsafe + idx;
                unsigned long long v;
                for (;;) {
                    v = load_u64_l2(fs);                 // (D) ~200cyc if co-XCD
                    if ((unsigned)(v >> 32) == (unsigned)t) break;
                    v = __hip_atomic_load(ss, __ATOMIC_RELAXED,
                                          __HIP_MEMORY_SCOPE_AGENT);
                    if ((unsigned)(v >> 32) == (unsigned)t) break;
                }
                ti[p][Iq + hh] = __uint_as_float((unsigned)(v & 0xffffffffu));
            }
            // own rows, t>0: written to LDS by critical of step t-1.
        }
        __syncthreads();                 // the only barrier per step

        const float* xpart = (t < PRE_S) ? (xall + t * Iq) : &ti[p][0];
        const float* hpart = &ti[p][Iq];

        // ---- critical: fused pre+nsq -> butterflies -> inv -> tanh -> publish
        float pre = 0.f, nsq = 0.f;
#pragma unroll
        for (int j = 0; j < 4; ++j) {
            const float4 tv = *(const float4*)&xpart[4 * lr + 64 * j];
            float tw;
            tw = fw[4*j+0] + ff[4*j+0]; pre = fmaf(tv.x, tw, pre); nsq = fmaf(tw, tw, nsq);
            tw = fw[4*j+1] + ff[4*j+1]; pre = fmaf(tv.y, tw, pre); nsq = fmaf(tw, tw, nsq);
            tw = fw[4*j+2] + ff[4*j+2]; pre = fmaf(tv.z, tw, pre); nsq = fmaf(tw, tw, nsq);
            tw = fw[4*j+3] + ff[4*j+3]; pre = fmaf(tv.w, tw, pre); nsq = fmaf(tw, tw, nsq);
        }
#pragma unroll
        for (int j = 4; j < 8; ++j) {
            const float4 tv = *(const float4*)&hpart[4 * lr + 64 * (j - 4)];
            float tw;
            tw = fw[4*j+0] + ff[4*j+0]; pre = fmaf(tv.x, tw, pre); nsq = fmaf(tw, tw, nsq);
            tw = fw[4*j+1] + ff[4*j+1]; pre = fmaf(tv.y, tw, pre); nsq = fmaf(tw, tw, nsq);
            tw = fw[4*j+2] + ff[4*j+2]; pre = fmaf(tv.z, tw, pre); nsq = fmaf(tw, tw, nsq);
            tw = fw[4*j+3] + ff[4*j+3]; pre = fmaf(tv.w, tw, pre); nsq = fmaf(tw, tw, nsq);
        }
#pragma unroll
        for (int m = 1; m < 16; m <<= 1) {
            pre += __shfl_xor(pre, m, 16);
            nsq += __shfl_xor(nsq, m, 16);
        }
        const float inv = __frsqrt_rn(nsq);          // (B) nsq >= |w_row|^2 > 0
        const float hn  = fast_tanh(fmaf(pre, inv, brow));

        if (lr == 0) {
            if (t < Sq - 1)
                ti[(t + 1) & 1][Iq + row] = hn;      // (A) local short-circuit
            const unsigned long long pk =
                ((unsigned long long)(unsigned)(t + 1) << 32) |
                (unsigned long long)__float_as_uint(hn);
            const size_t idx = (size_t)p * Bq * Hq + (size_t)b * Hq + row;
            store_u64_l2(hfast + idx, pk);           // (D) fast mirror (XCD L2)
            __hip_atomic_store(hsafe + idx, pk, __ATOMIC_RELAXED,
                               __HIP_MEMORY_SCOPE_AGENT);   // safe (MALL)
        }

        // ---- shadow: f update ----
#pragma unroll
        for (int j = 0; j < 4; ++j) {
            const float4 tv = *(const float4*)&xpart[4 * lr + 64 * j];
            ff[4*j+0] = fmaf(fl[4*j+0], ff[4*j+0] * inv, fg[4*j+0] * (hn * tv.x));
            ff[4*j+1] = fmaf(fl[4*j+1], ff[4*j+1] * inv, fg[4*j+1] * (hn * tv.y));
            ff[4*j+2] = fmaf(fl[4*j+2], ff[4*j+2] * inv, fg[4*j+2] * (hn * tv.z));
            ff[4*j+3] = fmaf(fl[4*j+3], ff[4*j+3] * inv, fg[4*j+3] * (hn * tv.w));
        }
#pragma unroll
        for (int j = 4; j < 8; ++j) {
            const float4 tv = *(const float4*)&hpart[4 * lr + 64 * (j - 4)];
            ff[4*j+0] = fmaf(fl[4*j+0], ff[4*j+0] * inv, fg[4*j+0] * (hn * tv.x));
            ff[4*j+1] = fmaf(fl[4*j+1], ff[4*j+1] * inv, fg[4*j+1] * (hn * tv.y));
            ff[4*j+2] = fmaf(fl[4*j+2], ff[4*j+2] * inv, fg[4*j+2] * (hn * tv.z));
            ff[4*j+3] = fmaf(fl[4*j+3], ff[4*j+3] * inv, fg[4*j+3] * (hn * tv.w));
        }
    }

    // ---- f_fin: 16 lanes x float4 per row chunk ----
    float* fo = out + Bq * Oq + Bq * Hq + (size_t)b * Hq * Fq + rowoff;
#pragma unroll
    for (int j = 0; j < 8; ++j) {
        const int c = 4 * lr + 64 * j;
        *(float4*)(fo + c) = *(const float4*)&ff[4*j];
    }

    // ---- epilogue (chunk-0 wg per batch): h_fin + tag_space ----
    if (chunk == 0) {
        if (tid < Hq) {
            const size_t idx = (size_t)1 * Bq * Hq + (size_t)b * Hq + tid;
            const unsigned long long* fs = hfast + idx;
            const unsigned long long* ss = hsafe + idx;
            unsigned long long v;
            for (;;) {
                v = load_u64_l2(fs);
                if ((unsigned)(v >> 32) == (unsigned)Sq) break;
                v = __hip_atomic_load(ss, __ATOMIC_RELAXED,
                                      __HIP_MEMORY_SCOPE_AGENT);
                if ((unsigned)(v >> 32) == (unsigned)Sq) break;
            }
            const float hv = __uint_as_float((unsigned)(v & 0xffffffffu));
            ti[0][tid] = hv;                              // ti[0] is free here
            out[Bq * Oq + (size_t)b * Hq + tid] = hv;     // h_fin
        }
        __syncthreads();
        // 512 threads = 128 outputs x 4 lanes; lane l sums cols 16k+4l..+3.
        const int o = tid >> 2;
        const int l = tid & 3;
        const float* wr = ow + (size_t)o * Hq;
        float acc = 0.f;
#pragma unroll
        for (int k = 0; k < 16; ++k) {
            const int cc = 16 * k + 4 * l;
            const float4 w4 = *(const float4*)(wr + cc);
            const float4 h4 = *(const float4*)&ti[0][cc];
            acc += w4.x * h4.x + w4.y * h4.y + w4.z * h4.z + w4.w * h4.w;
        }
        acc += __shfl_xor(acc, 1, 4);
        acc += __shfl_xor(acc, 2, 4);
        if (l == 0) out[(size_t)b * Oq + o] = acc + ob[o];
    }
}

extern "C" void kernel_launch(void* const* d_in, const int* in_sizes, int n_in,
                              void* d_out, int out_size, void* d_ws, size_t ws_size,
                              hipStream_t stream)
{
    const float* x    = (const float*)d_in[0];
    const float* w    = (const float*)d_in[1];
    const float* wl   = (const float*)d_in[2];
    const float* wgm  = (const float*)d_in[3];
    const float* bias = (const float*)d_in[4];
    const float* ow   = (const float*)d_in[5];
    const float* ob   = (const float*)d_in[6];
    float* out = (float*)d_out;

    // Zero safe + fast (tag,val) slots: 2 regions x 2*B*H x 8B = 256 KB.
    hipMemsetAsync(d_ws, 0, 4 * Bq * Hq * sizeof(unsigned long long), stream);

    stpn_main<<<Bq * WPB, NT, 0, stream>>>(x, w, wl, wgm, bias, ow, ob, out,
                                           (unsigned long long*)d_ws);
}